// Round 1
// baseline (988.792 us; speedup 1.0000x reference)
//
#include <hip/hip_runtime.h>
#include <hip/hip_bf16.h>

#define BN_EPS 1e-5f

// ---------------- edge aggregation, layer 1 (20 raw features) ----------------
__global__ __launch_bounds__(256) void k_edge_agg20(
    const int* __restrict__ srcA, const int* __restrict__ dstA,
    const float* __restrict__ xs, const float* __restrict__ xt,
    float* __restrict__ agg, float* __restrict__ deg, int E) {
  long gtid = (long)blockIdx.x * blockDim.x + threadIdx.x;
  int f = (int)(gtid & 31);
  long e = gtid >> 5;
  if (e >= E) return;
  int s = srcA[e], d = dstA[e];
  if (f < 20) {
    float v = (f < 6) ? xs[(long)s * 6 + f] : xt[(long)s * 14 + (f - 6)];
    atomicAdd(&agg[(long)d * 20 + f], v);
  }
  if (f == 0) atomicAdd(&deg[d], 1.0f);
}

// ---------------- SAGE1: h1 = mean@W1l + b1l + x@W1r  ([N,64]) --------------
__global__ __launch_bounds__(256) void k_sage1(
    const float* __restrict__ agg, const float* __restrict__ deg,
    const float* __restrict__ xs, const float* __restrict__ xt,
    const float* __restrict__ W1l, const float* __restrict__ b1l,
    const float* __restrict__ W1r, float* __restrict__ h1, int N) {
  __shared__ float sWl[20 * 64], sWr[20 * 64];
  __shared__ float sm[4][20], sx[4][20];
  int tid = threadIdx.x;
  for (int i = tid; i < 1280; i += 256) { sWl[i] = W1l[i]; sWr[i] = W1r[i]; }
  int ln = tid >> 6, c = tid & 63;
  int n = blockIdx.x * 4 + ln;
  if (n < N && c < 20) {
    float dv = fmaxf(deg[n], 1.0f);
    sm[ln][c] = agg[(long)n * 20 + c] / dv;
    sx[ln][c] = (c < 6) ? xs[(long)n * 6 + c] : xt[(long)n * 14 + (c - 6)];
  }
  __syncthreads();
  if (n < N) {
    float acc = b1l[c];
#pragma unroll
    for (int f = 0; f < 20; ++f)
      acc += sm[ln][f] * sWl[f * 64 + c] + sx[ln][f] * sWr[f * 64 + c];
    h1[(long)n * 64 + c] = acc;
  }
}

// ---------------- per-channel sum / sumsq over nodes ------------------------
__global__ __launch_bounds__(256) void k_stats(
    const float* __restrict__ h, int N, int C,
    float* __restrict__ sum, float* __restrict__ sq) {
  int tid = threadIdx.x;
  int rows = 256 / C;
  int c = tid % C, r = tid / C;
  float s = 0.f, q = 0.f;
  for (long n = (long)blockIdx.x * rows + r; n < N; n += (long)gridDim.x * rows) {
    float v = h[n * C + c];
    s += v; q += v * v;
  }
  __shared__ float ls[256], lq[256];
  ls[tid] = s; lq[tid] = q;
  __syncthreads();
  if (r == 0) {
    for (int rr = 1; rr < rows; ++rr) { s += ls[c + rr * C]; q += lq[c + rr * C]; }
    atomicAdd(&sum[c], s);
    atomicAdd(&sq[c], q);
  }
}

// -------- BN1 + ReLU + dual projection p2l=h@W2l, p2r=h@W2r  ([N,32]) -------
__global__ __launch_bounds__(256) void k_bn1_proj(
    const float* __restrict__ h1,
    const float* __restrict__ sum, const float* __restrict__ sq,
    const float* __restrict__ g, const float* __restrict__ be,
    const float* __restrict__ W2l, const float* __restrict__ W2r,
    float* __restrict__ p2l, float* __restrict__ p2r, int N) {
  __shared__ float sWl[64 * 32], sWr[64 * 32];
  __shared__ float sh[8][64];
  __shared__ float sscale[64], sshift[64];
  int tid = threadIdx.x;
  for (int i = tid; i < 2048; i += 256) { sWl[i] = W2l[i]; sWr[i] = W2r[i]; }
  if (tid < 64) {
    float m = sum[tid] * (1.0f / (float)N);
    float v = sq[tid] * (1.0f / (float)N) - m * m;
    float inv = rsqrtf(v + BN_EPS);
    float sc = g[tid] * inv;
    sscale[tid] = sc;
    sshift[tid] = be[tid] - m * sc;
  }
  __syncthreads();
  long base = (long)blockIdx.x * 512;
#pragma unroll
  for (int k = 0; k < 2; ++k) {
    long j = base + tid + k * 256;
    if (j < (long)N * 64) {
      int c = (int)(j & 63);
      float v = h1[j] * sscale[c] + sshift[c];
      sh[(tid + k * 256) >> 6][c] = fmaxf(v, 0.f);
    }
  }
  __syncthreads();
  int c2 = tid & 31, ln = tid >> 5;
  int n = blockIdx.x * 8 + ln;
  if (n < N) {
    float al = 0.f, ar = 0.f;
#pragma unroll
    for (int c = 0; c < 64; ++c) {
      float hv = sh[ln][c];
      al += hv * sWl[c * 32 + c2];
      ar += hv * sWr[c * 32 + c2];
    }
    p2l[(long)n * 32 + c2] = al;
    p2r[(long)n * 32 + c2] = ar;
  }
}

// ---------------- edge aggregation, layer 2 (32 projected features) ---------
__global__ __launch_bounds__(256) void k_edge_agg32(
    const int* __restrict__ srcA, const int* __restrict__ dstA,
    const float* __restrict__ p, float* __restrict__ agg, int E) {
  long gtid = (long)blockIdx.x * blockDim.x + threadIdx.x;
  int f = (int)(gtid & 31);
  long e = gtid >> 5;
  if (e >= E) return;
  int s = srcA[e], d = dstA[e];
  atomicAdd(&agg[(long)d * 32 + f], p[(long)s * 32 + f]);
}

// ---------------- h2 = agg2/deg + b2l + p2r  ([N,32]) -----------------------
__global__ __launch_bounds__(256) void k_h2(
    const float* __restrict__ agg, const float* __restrict__ deg,
    const float* __restrict__ b2l, const float* __restrict__ p2r,
    float* __restrict__ h2, int N) {
  long i = (long)blockIdx.x * blockDim.x + threadIdx.x;
  if (i >= (long)N * 32) return;
  int n = (int)(i >> 5), f = (int)(i & 31);
  float dv = fmaxf(deg[n], 1.0f);
  h2[i] = agg[i] / dv + b2l[f] + p2r[i];
}

// ---------------- BN2 + ReLU + channel-mean + MLP head ----------------------
__global__ __launch_bounds__(256) void k_final(
    const float* __restrict__ h2,
    const float* __restrict__ sum, const float* __restrict__ sq,
    const float* __restrict__ g, const float* __restrict__ be,
    const float* __restrict__ Wp, const float* __restrict__ bp,
    const float* __restrict__ Wo, const float* __restrict__ bo,
    float* __restrict__ out, int N) {
  int tid = threadIdx.x;
  int c = tid & 31, ln = tid >> 5;
  int n = blockIdx.x * 8 + ln;
  if (n >= N) return;
  float m = sum[c] * (1.0f / (float)N);
  float v = sq[c] * (1.0f / (float)N) - m * m;
  float inv = rsqrtf(v + BN_EPS);
  float sc = g[c] * inv;
  float sh = be[c] - m * sc;
  float x = h2[(long)n * 32 + c] * sc + sh;
  x = fmaxf(x, 0.f);
#pragma unroll
  for (int msk = 16; msk >= 1; msk >>= 1) x += __shfl_xor(x, msk);
  float lr = x * (1.0f / 32.0f);
  float e = fmaxf(lr * Wp[c] + bp[c], 0.f) * Wo[c];
#pragma unroll
  for (int msk = 16; msk >= 1; msk >>= 1) e += __shfl_xor(e, msk);
  if (c == 0) out[n] = e + bo[0];
}

extern "C" void kernel_launch(void* const* d_in, const int* in_sizes, int n_in,
                              void* d_out, int out_size, void* d_ws, size_t ws_size,
                              hipStream_t stream) {
  const float* xs  = (const float*)d_in[0];
  const float* xt  = (const float*)d_in[1];
  const int*   ei  = (const int*)d_in[2];
  const float* W1l = (const float*)d_in[3];
  const float* b1l = (const float*)d_in[4];
  const float* W1r = (const float*)d_in[5];
  const float* g1  = (const float*)d_in[6];
  const float* be1 = (const float*)d_in[7];
  const float* W2l = (const float*)d_in[8];
  const float* b2l = (const float*)d_in[9];
  const float* W2r = (const float*)d_in[10];
  const float* g2  = (const float*)d_in[11];
  const float* be2 = (const float*)d_in[12];
  const float* Wp  = (const float*)d_in[13];
  const float* bp  = (const float*)d_in[14];
  const float* Wo  = (const float*)d_in[15];
  const float* bo  = (const float*)d_in[16];
  float* out = (float*)d_out;

  int N = in_sizes[0] / 6;
  int E = in_sizes[2] / 2;
  const int* srcA = ei;
  const int* dstA = ei + E;

  // workspace layout (floats): deg[N] | agg1[20N] | h1[64N] (reused: agg2[32N], h2[32N]) |
  //                            p2l[32N] | p2r[32N] | stats[192]
  float* ws   = (float*)d_ws;
  float* deg  = ws;
  float* agg1 = deg + N;
  float* h1   = agg1 + (long)20 * N;
  float* agg2 = h1;                    // alias: h1 dead after k_bn1_proj
  float* h2   = h1 + (long)32 * N;
  float* p2l  = h1 + (long)64 * N;
  float* p2r  = p2l + (long)32 * N;
  float* stats = p2r + (long)32 * N;
  float* sum1 = stats, * sq1 = stats + 64, * sum2 = stats + 128, * sq2 = stats + 160;

  hipMemsetAsync(deg, 0, sizeof(float) * (size_t)(21 * (long)N), stream);
  hipMemsetAsync(stats, 0, sizeof(float) * 192, stream);

  const int tb = 256;
  long t1 = (long)E * 32;
  int eblocks = (int)((t1 + tb - 1) / tb);

  k_edge_agg20<<<eblocks, tb, 0, stream>>>(srcA, dstA, xs, xt, agg1, deg, E);
  k_sage1<<<(N + 3) / 4, tb, 0, stream>>>(agg1, deg, xs, xt, W1l, b1l, W1r, h1, N);
  k_stats<<<1024, tb, 0, stream>>>(h1, N, 64, sum1, sq1);
  k_bn1_proj<<<(N + 7) / 8, tb, 0, stream>>>(h1, sum1, sq1, g1, be1, W2l, W2r, p2l, p2r, N);
  hipMemsetAsync(agg2, 0, sizeof(float) * (size_t)(32 * (long)N), stream);
  k_edge_agg32<<<eblocks, tb, 0, stream>>>(srcA, dstA, p2l, agg2, E);
  k_h2<<<(int)(((long)32 * N + tb - 1) / tb), tb, 0, stream>>>(agg2, deg, b2l, p2r, h2, N);
  k_stats<<<1024, tb, 0, stream>>>(h2, N, 32, sum2, sq2);
  k_final<<<(N + 7) / 8, tb, 0, stream>>>(h2, sum2, sq2, g2, be2, Wp, bp, Wo, bo, out, N);
}